// Round 1
// baseline (827.711 us; speedup 1.0000x reference)
//
#include <hip/hip_runtime.h>

// ---------------------------------------------------------------------------
// LoRA QKV fused projection on MI355X (gfx950)
//   q = x @ Wq^T + 2*(x@Aq)@Bq + bq   [8192, 4096]
//   k = x @ Wk^T + 2*(x@Ak)@Bk + bk   [8192, 1024]
//   v = x @ Wv^T + 2*(x@Av)@Bv + bv   [8192, 1024]
// Strategy: fold LoRA into effective weight Weff[o,h] = W[o,h] + 2*sum_r A[h,r]B[r,o],
// convert X and Weff to bf16 in d_ws, run ONE 128x128-tile bf16 MFMA GEMM
// (m97 structure: global_load_lds width-16 staging, 16x16x32 MFMA, 4x4 frags/wave),
// epilogue adds fp32 bias and scatters into the q/k/v output regions.
// ---------------------------------------------------------------------------

#define GLOBAL_AS __attribute__((address_space(1)))
#define LDS_AS    __attribute__((address_space(3)))

typedef __attribute__((ext_vector_type(8))) short  short8;   // 8 bf16 = 4 VGPRs (MFMA A/B frag)
typedef __attribute__((ext_vector_type(4))) float  floatx4;  // MFMA C/D frag

constexpr int Mdim = 8192;   // B*S
constexpr int Kdim = 4096;   // H
constexpr int NQ   = 4096;   // Q_DIM
constexpr int NKV  = 1024;   // KV_DIM
constexpr int NTOT = NQ + 2 * NKV;  // 6144
constexpr float LORA_SCALE = 2.0f;  // 32/16

constexpr int BM = 128, BN = 128, BK = 32;
constexpr int TILES_M = Mdim / BM;   // 64
constexpr int TILES_N = NTOT / BN;   // 48
constexpr int NWG = TILES_M * TILES_N;  // 3072 (multiple of 8 -> simple XCD swizzle bijective)

// round-to-nearest-even f32 -> bf16 bits (inputs are finite)
__device__ __forceinline__ unsigned short f2bf(float f) {
    union { float f; unsigned int u; } a; a.f = f;
    unsigned int r = a.u + 0x7FFFu + ((a.u >> 16) & 1u);
    return (unsigned short)(r >> 16);
}

// ---------------------------------------------------------------------------
// Kernel 1: fp32 -> bf16 conversion (vectorized: float4 in, ushort4 out)
// ---------------------------------------------------------------------------
__global__ __launch_bounds__(256)
void cvt_bf16_kernel(const float4* __restrict__ in, ushort4* __restrict__ out, int n4) {
    int i = blockIdx.x * 256 + threadIdx.x;
    const int stride = gridDim.x * 256;
    for (; i < n4; i += stride) {
        float4 v = in[i];
        ushort4 u;
        u.x = f2bf(v.x); u.y = f2bf(v.y); u.z = f2bf(v.z); u.w = f2bf(v.w);
        out[i] = u;
    }
}

// ---------------------------------------------------------------------------
// Kernel 2: build Weff (bf16) with folded LoRA.
//   Weff[n, h] = W[n, h] + 2 * sum_{r<16} A[h, r] * B[r, n]
// One wave per output row n; lane handles 4 consecutive h per iter.
// ---------------------------------------------------------------------------
__global__ __launch_bounds__(256)
void build_weff_kernel(const float* __restrict__ Wq, const float* __restrict__ Wk,
                       const float* __restrict__ Wv,
                       const float* __restrict__ Aq, const float* __restrict__ Bq,
                       const float* __restrict__ Ak, const float* __restrict__ Bk,
                       const float* __restrict__ Av, const float* __restrict__ Bv,
                       unsigned short* __restrict__ Wf) {
    const int wave = threadIdx.x >> 6;
    const int lane = threadIdx.x & 63;
    const int n = blockIdx.x * 4 + wave;          // 0..6143

    const float* W; const float* A; const float* Bm; int O; int nn;
    if (n < NQ)            { W = Wq; A = Aq; Bm = Bq; O = NQ;  nn = n; }
    else if (n < NQ + NKV) { W = Wk; A = Ak; Bm = Bk; O = NKV; nn = n - NQ; }
    else                   { W = Wv; A = Av; Bm = Bv; O = NKV; nn = n - NQ - NKV; }

    // B column for this n, LoRA scaling folded in (broadcast loads, L2-resident)
    float4 bc[4];
    #pragma unroll
    for (int q = 0; q < 4; ++q) {
        bc[q].x = Bm[(q * 4 + 0) * O + nn] * LORA_SCALE;
        bc[q].y = Bm[(q * 4 + 1) * O + nn] * LORA_SCALE;
        bc[q].z = Bm[(q * 4 + 2) * O + nn] * LORA_SCALE;
        bc[q].w = Bm[(q * 4 + 3) * O + nn] * LORA_SCALE;
    }

    const float* wrow = W + (size_t)nn * Kdim;
    unsigned short* orow = Wf + (size_t)n * Kdim;

    for (int i = 0; i < Kdim / 256; ++i) {
        const int h = i * 256 + lane * 4;
        const float4 w4 = *reinterpret_cast<const float4*>(wrow + h);
        float o[4];
        const float wv[4] = { w4.x, w4.y, w4.z, w4.w };
        #pragma unroll
        for (int j = 0; j < 4; ++j) {
            const float4* a4 = reinterpret_cast<const float4*>(A + (size_t)(h + j) * 16);
            float d = 0.f;
            #pragma unroll
            for (int q = 0; q < 4; ++q) {
                float4 a = a4[q];
                d += a.x * bc[q].x + a.y * bc[q].y + a.z * bc[q].z + a.w * bc[q].w;
            }
            o[j] = wv[j] + d;
        }
        ushort4 u;
        u.x = f2bf(o[0]); u.y = f2bf(o[1]); u.z = f2bf(o[2]); u.w = f2bf(o[3]);
        *reinterpret_cast<ushort4*>(orow + h) = u;
    }
}

// ---------------------------------------------------------------------------
// Kernel 3: bf16 GEMM, B^T layout (both X and Weff are [rows, K] row-major).
// m97 structure: 128x128 tile, BK=32, 4 waves (2x2), each wave 64x64 via
// 4x4 frags of 16x16x32 MFMA. global_load_lds width=16 staging, 2 barriers/iter.
// Epilogue: + bias, scatter to q/k/v regions of out.
// ---------------------------------------------------------------------------
__global__ __launch_bounds__(256, 2)
void gemm_qkv_kernel(const unsigned short* __restrict__ X,   // [Mdim, Kdim] bf16
                     const unsigned short* __restrict__ Wf,  // [NTOT, Kdim] bf16
                     const float* __restrict__ bq, const float* __restrict__ bk,
                     const float* __restrict__ bv,
                     float* __restrict__ out) {
    __shared__ __align__(16) unsigned short As[BM * BK];  // 8 KB
    __shared__ __align__(16) unsigned short Bs[BN * BK];  // 8 KB

    const int tid  = threadIdx.x;
    const int lane = tid & 63;
    const int wave = tid >> 6;

    // XCD-aware swizzle (NWG % 8 == 0 -> bijective)
    int bid = blockIdx.x;
    bid = (bid & 7) * (NWG / 8) + (bid >> 3);
    const int bm = bid / TILES_N;
    const int bn = bid % TILES_N;
    const int row0 = bm * BM;
    const int col0 = bn * BN;

    floatx4 acc[4][4];
    #pragma unroll
    for (int i = 0; i < 4; ++i)
        #pragma unroll
        for (int j = 0; j < 4; ++j)
            acc[i][j] = (floatx4){0.f, 0.f, 0.f, 0.f};

    const int wm = wave >> 1;       // 0..1
    const int wn = wave & 1;        // 0..1

    // staging decomposition: 16 chunks of 1KB per tile pair; each wave issues
    // 2 A-chunks + 2 B-chunks. lane covers 16B: row = chunk*16 + lane/4,
    // k-offset = (lane%4)*8 elements.
    const int rA = lane >> 2;
    const int kA = (lane & 3) * 8;

    for (int k0 = 0; k0 < Kdim; k0 += BK) {
        #pragma unroll
        for (int q = 0; q < 2; ++q) {
            const int chunk = wave * 2 + q;
            const unsigned short* src = X + (size_t)(row0 + chunk * 16 + rA) * Kdim + k0 + kA;
            __builtin_amdgcn_global_load_lds((const GLOBAL_AS void*)src,
                                             (LDS_AS void*)&As[chunk * 512], 16, 0, 0);
        }
        #pragma unroll
        for (int q = 0; q < 2; ++q) {
            const int chunk = wave * 2 + q;
            const unsigned short* src = Wf + (size_t)(col0 + chunk * 16 + rA) * Kdim + k0 + kA;
            __builtin_amdgcn_global_load_lds((const GLOBAL_AS void*)src,
                                             (LDS_AS void*)&Bs[chunk * 512], 16, 0, 0);
        }
        __syncthreads();

        short8 af[4], bf[4];
        #pragma unroll
        for (int mf = 0; mf < 4; ++mf) {
            const int r = wm * 64 + mf * 16 + (lane & 15);
            af[mf] = *reinterpret_cast<const short8*>(&As[r * BK + ((lane >> 4) * 8)]);
        }
        #pragma unroll
        for (int nf = 0; nf < 4; ++nf) {
            const int r = wn * 64 + nf * 16 + (lane & 15);
            bf[nf] = *reinterpret_cast<const short8*>(&Bs[r * BK + ((lane >> 4) * 8)]);
        }
        #pragma unroll
        for (int mf = 0; mf < 4; ++mf)
            #pragma unroll
            for (int nf = 0; nf < 4; ++nf)
                acc[mf][nf] = __builtin_amdgcn_mfma_f32_16x16x32_bf16(
                                  af[mf], bf[nf], acc[mf][nf], 0, 0, 0);
        __syncthreads();
    }

    // ---- epilogue: bias + scatter into q/k/v regions ----
    float* obase; int ldo; const float* bias; int cofs;
    if (col0 < NQ) {
        obase = out;                                  ldo = NQ;  bias = bq; cofs = 0;
    } else if (col0 < NQ + NKV) {
        obase = out + (size_t)Mdim * NQ;              ldo = NKV; bias = bk; cofs = NQ;
    } else {
        obase = out + (size_t)Mdim * (NQ + NKV);      ldo = NKV; bias = bv; cofs = NQ + NKV;
    }

    #pragma unroll
    for (int nf = 0; nf < 4; ++nf) {
        const int col = col0 + wn * 64 + nf * 16 + (lane & 15) - cofs;
        const float b = bias[col];
        #pragma unroll
        for (int mf = 0; mf < 4; ++mf) {
            #pragma unroll
            for (int r = 0; r < 4; ++r) {
                const int row = row0 + wm * 64 + mf * 16 + (lane >> 4) * 4 + r;
                obase[(size_t)row * ldo + col] = acc[mf][nf][r] + b;
            }
        }
    }
}

// ---------------------------------------------------------------------------
extern "C" void kernel_launch(void* const* d_in, const int* in_sizes, int n_in,
                              void* d_out, int out_size, void* d_ws, size_t ws_size,
                              hipStream_t stream) {
    const float* x  = (const float*)d_in[0];
    const float* Wq = (const float*)d_in[1];
    const float* Wk = (const float*)d_in[2];
    const float* Wv = (const float*)d_in[3];
    const float* bq = (const float*)d_in[4];
    const float* bk = (const float*)d_in[5];
    const float* bv = (const float*)d_in[6];
    const float* Aq = (const float*)d_in[7];
    const float* Bq = (const float*)d_in[8];
    const float* Ak = (const float*)d_in[9];
    const float* Bk = (const float*)d_in[10];
    const float* Av = (const float*)d_in[11];
    const float* Bv = (const float*)d_in[12];
    float* out = (float*)d_out;

    unsigned short* Xbf = (unsigned short*)d_ws;                   // 64 MB
    unsigned short* Wf  = Xbf + (size_t)Mdim * Kdim;               // 48 MB

    // 1) X -> bf16
    cvt_bf16_kernel<<<2048, 256, 0, stream>>>(
        (const float4*)x, (ushort4*)Xbf, Mdim * Kdim / 4);

    // 2) Weff (bf16) with folded LoRA
    build_weff_kernel<<<NTOT / 4, 256, 0, stream>>>(
        Wq, Wk, Wv, Aq, Bq, Ak, Bk, Av, Bv, Wf);

    // 3) single fused GEMM + bias + scatter
    gemm_qkv_kernel<<<NWG, 256, 0, stream>>>(Xbf, Wf, bq, bk, bv, out);
}

// Round 3
// 693.595 us; speedup vs baseline: 1.1934x; 1.1934x over previous
//
#include <hip/hip_runtime.h>

// ---------------------------------------------------------------------------
// LoRA QKV fused projection on MI355X (gfx950)
// Weff-folding (LoRA into weights) + ONE bf16 MFMA GEMM.
// GEMM: 256x256 tile, 8 waves, 8-phase schedule with counted vmcnt (T3+T4),
// both-sides LDS XOR swizzle (T2), s_setprio around MFMA (T5).
// K is processed as 128 slices of 32; LDS = ring of 4 slices per matrix.
//
// R2 fix: global_load_lds LDS dest is wave-uniform base + lane*16 — the dest
// base must be PER-WAVE (&buf[w*512]); R1 passed one base for all 8 waves so
// 7/8 of each slice was never written (NaN from uninit LDS).
// ---------------------------------------------------------------------------

#define GLOBAL_AS __attribute__((address_space(1)))
#define LDS_AS    __attribute__((address_space(3)))

typedef __attribute__((ext_vector_type(8))) short  short8;   // 8 bf16 (MFMA A/B frag)
typedef __attribute__((ext_vector_type(4))) float  floatx4;  // MFMA C/D frag

constexpr int Mdim = 8192;   // B*S
constexpr int Kdim = 4096;   // H
constexpr int NQ   = 4096;
constexpr int NKV  = 1024;
constexpr int NTOT = NQ + 2 * NKV;  // 6144
constexpr float LORA_SCALE = 2.0f;

constexpr int BM = 256, BN = 256;
constexpr int TILES_M = Mdim / BM;      // 32
constexpr int TILES_N = NTOT / BN;      // 24
constexpr int NWG = TILES_M * TILES_N;  // 768 (%8==0 -> bijective XCD swizzle)
constexpr int NSLICE = Kdim / 32;       // 128 K-slices of 32

constexpr int WEFF_BLOCKS = NTOT / 4;   // 1536
constexpr int CVT_BLOCKS  = 2048;

__device__ __forceinline__ unsigned short f2bf(float f) {
    union { float f; unsigned int u; } a; a.f = f;
    unsigned int r = a.u + 0x7FFFu + ((a.u >> 16) & 1u);
    return (unsigned short)(r >> 16);
}

// ---------------------------------------------------------------------------
// Fused prep: blocks [0, WEFF_BLOCKS) build Weff (bf16, LoRA folded);
// blocks [WEFF_BLOCKS, +CVT_BLOCKS) convert X fp32 -> bf16.
// ---------------------------------------------------------------------------
__global__ __launch_bounds__(256)
void prep_kernel(const float4* __restrict__ x4, unsigned short* __restrict__ Xbf,
                 const float* __restrict__ Wq, const float* __restrict__ Wk,
                 const float* __restrict__ Wv,
                 const float* __restrict__ Aq, const float* __restrict__ Bq,
                 const float* __restrict__ Ak, const float* __restrict__ Bk,
                 const float* __restrict__ Av, const float* __restrict__ Bv,
                 unsigned short* __restrict__ Wf) {
    if (blockIdx.x >= WEFF_BLOCKS) {
        // ---- X fp32 -> bf16 (vectorized) ----
        int i = (blockIdx.x - WEFF_BLOCKS) * 256 + threadIdx.x;
        const int stride = CVT_BLOCKS * 256;
        const int n4 = Mdim * Kdim / 4;
        ushort4* out = (ushort4*)Xbf;
        for (; i < n4; i += stride) {
            float4 v = x4[i];
            ushort4 u;
            u.x = f2bf(v.x); u.y = f2bf(v.y); u.z = f2bf(v.z); u.w = f2bf(v.w);
            out[i] = u;
        }
        return;
    }
    // ---- Weff[n,h] = W[n,h] + 2 * sum_r A[h,r] B[r,n]  (one wave per row n) ----
    const int wave = threadIdx.x >> 6;
    const int lane = threadIdx.x & 63;
    const int n = blockIdx.x * 4 + wave;

    const float* W; const float* A; const float* Bm; int O; int nn;
    if (n < NQ)            { W = Wq; A = Aq; Bm = Bq; O = NQ;  nn = n; }
    else if (n < NQ + NKV) { W = Wk; A = Ak; Bm = Bk; O = NKV; nn = n - NQ; }
    else                   { W = Wv; A = Av; Bm = Bv; O = NKV; nn = n - NQ - NKV; }

    float4 bc[4];
    #pragma unroll
    for (int q = 0; q < 4; ++q) {
        bc[q].x = Bm[(q * 4 + 0) * O + nn] * LORA_SCALE;
        bc[q].y = Bm[(q * 4 + 1) * O + nn] * LORA_SCALE;
        bc[q].z = Bm[(q * 4 + 2) * O + nn] * LORA_SCALE;
        bc[q].w = Bm[(q * 4 + 3) * O + nn] * LORA_SCALE;
    }

    const float* wrow = W + (size_t)nn * Kdim;
    unsigned short* orow = Wf + (size_t)n * Kdim;

    for (int i = 0; i < Kdim / 256; ++i) {
        const int h = i * 256 + lane * 4;
        const float4 w4 = *reinterpret_cast<const float4*>(wrow + h);
        const float wv[4] = { w4.x, w4.y, w4.z, w4.w };
        float o[4];
        #pragma unroll
        for (int j = 0; j < 4; ++j) {
            const float4* a4 = reinterpret_cast<const float4*>(A + (size_t)(h + j) * 16);
            float d = 0.f;
            #pragma unroll
            for (int q = 0; q < 4; ++q) {
                float4 a = a4[q];
                d += a.x * bc[q].x + a.y * bc[q].y + a.z * bc[q].z + a.w * bc[q].w;
            }
            o[j] = wv[j] + d;
        }
        ushort4 u;
        u.x = f2bf(o[0]); u.y = f2bf(o[1]); u.z = f2bf(o[2]); u.w = f2bf(o[3]);
        *reinterpret_cast<ushort4*>(orow + h) = u;
    }
}

// ---------------------------------------------------------------------------
// GEMM: out[M, NTOT] = Xbf[M,K] . Wf[NTOT,K]^T + bias, scattered to q/k/v.
//
// LDS: A/B each a ring of 4 K-slices; slice = 256 rows x 32 k (16 KB),
// laid out as 2 halves of 128 rows; element (half, r, chunk c) at byte
// half*8192 + r*64 + c*16; phys chunk c holds source k-chunk c^((r>>1)&3).
// Wave w stages rows [w*16, w*16+16) of each half: dest base buf + half*8192
// + w*1024 bytes, lane l -> +l*16 (linear DMA); source k pre-permuted.
// Per-iteration (4 slices, 8 phases) ledger:
//   phase 0: compute g0+0/Mh0, stage A(g0+3)   phase 4: compute g0+2/Mh0, stage A(g0+5)
//   phase 1: compute g0+0/Mh1, stage B(g0+3)   phase 5: compute g0+2/Mh1, stage B(g0+5)
//   phase 2: compute g0+1/Mh0, stage A(g0+4)   phase 6: compute g0+3/Mh0, stage A(g0+6)
//   phase 3: compute g0+1/Mh1, stage B(g0+4)   phase 7: compute g0+3/Mh1, stage B(g0+6)
//   vmcnt(4) at end of phases 3 and 7 (retires exactly the 2 slices the next
//   4 phases consume; 1 slice = 4 loads stays in flight). Never vmcnt(0).
// ---------------------------------------------------------------------------
__global__ __launch_bounds__(512, 2)
void gemm_qkv_kernel(const unsigned short* __restrict__ X,
                     const unsigned short* __restrict__ Wf,
                     const float* __restrict__ bq, const float* __restrict__ bk,
                     const float* __restrict__ bv,
                     float* __restrict__ out) {
    __shared__ __align__(16) unsigned short Abuf[4][8192];  // 64 KB
    __shared__ __align__(16) unsigned short Bbuf[4][8192];  // 64 KB

    const int tid  = threadIdx.x;
    const int lane = tid & 63;
    const int w    = tid >> 6;
    const int wr   = w >> 2;        // 0..1  (M half)
    const int wc   = w & 3;         // 0..3  (N quarter)

    int bid = blockIdx.x;
    bid = (bid & 7) * (NWG / 8) + (bid >> 3);   // XCD-aware, bijective (768%8==0)
    const int row0 = (bid / TILES_N) * BM;
    const int col0 = (bid % TILES_N) * BN;

    // ds_read addressing (swizzled): frag row block at +1024B steps,
    // lane reads row (lane&15), k-chunk kh=lane>>4 from phys chunk kh^((row>>1)&3)
    const int swz    = (((lane >> 4) ^ ((lane >> 1) & 3)) << 4);    // bytes
    const int aByte0 = (wr * 128 + (lane & 15)) * 64 + swz;
    const int bByte0 = (wc * 64  + (lane & 15)) * 64 + swz;

    // staging source addressing (pre-permuted k so linear LDS dest ends swizzled)
    const int srow = (w << 4) + (lane >> 2);                         // 0..127
    const int kswz = (((lane & 3) ^ ((lane >> 3) & 3)) << 3);        // elements
    const unsigned short* pA0 = X  + (size_t)(row0 + srow) * Kdim + kswz;
    const unsigned short* pA1 = pA0 + (size_t)128 * Kdim;
    const unsigned short* pB0 = Wf + (size_t)(col0 + srow) * Kdim + kswz;
    const unsigned short* pB1 = pB0 + (size_t)128 * Kdim;

    floatx4 acc[8][4];
    #pragma unroll
    for (int i = 0; i < 8; ++i)
        #pragma unroll
        for (int j = 0; j < 4; ++j)
            acc[i][j] = (floatx4){0.f, 0.f, 0.f, 0.f};

    short8 bf[4];

#define STAGE(MATA, SS)                                                          \
    { const int ss_ = (SS) & (NSLICE - 1); const int st_ = (SS) & 3;             \
      if (MATA) {                                                                \
        __builtin_amdgcn_global_load_lds((const GLOBAL_AS void*)(pA0 + ss_ * 32),\
            (LDS_AS void*)(&Abuf[st_][w * 512]),        16, 0, 0);               \
        __builtin_amdgcn_global_load_lds((const GLOBAL_AS void*)(pA1 + ss_ * 32),\
            (LDS_AS void*)(&Abuf[st_][4096 + w * 512]), 16, 0, 0);               \
      } else {                                                                   \
        __builtin_amdgcn_global_load_lds((const GLOBAL_AS void*)(pB0 + ss_ * 32),\
            (LDS_AS void*)(&Bbuf[st_][w * 512]),        16, 0, 0);               \
        __builtin_amdgcn_global_load_lds((const GLOBAL_AS void*)(pB1 + ss_ * 32),\
            (LDS_AS void*)(&Bbuf[st_][4096 + w * 512]), 16, 0, 0);               \
      } }

#define DO_PHASE(G, MH, SMATA, SS, DOWAIT)                                       \
    {                                                                            \
      const int slot_ = (G) & 3;                                                 \
      const char* abase_ = (const char*)Abuf + slot_ * 16384;                    \
      short8 af[4];                                                              \
      _Pragma("unroll")                                                          \
      for (int mf = 0; mf < 4; ++mf)                                             \
        af[mf] = *(const short8*)(abase_ + aByte0 + ((MH) * 4 + mf) * 1024);     \
      if ((MH) == 0) {                                                           \
        const char* bbase_ = (const char*)Bbuf + slot_ * 16384;                  \
        _Pragma("unroll")                                                        \
        for (int nf = 0; nf < 4; ++nf)                                           \
          bf[nf] = *(const short8*)(bbase_ + bByte0 + nf * 1024);                \
      }                                                                          \
      STAGE(SMATA, SS);                                                          \
      __builtin_amdgcn_s_barrier();                                              \
      asm volatile("s_waitcnt lgkmcnt(0)");                                      \
      __builtin_amdgcn_s_setprio(1);                                             \
      _Pragma("unroll")                                                          \
      for (int mf = 0; mf < 4; ++mf)                                             \
        _Pragma("unroll")                                                        \
        for (int nf = 0; nf < 4; ++nf)                                           \
          acc[(MH) * 4 + mf][nf] = __builtin_amdgcn_mfma_f32_16x16x32_bf16(      \
              af[mf], bf[nf], acc[(MH) * 4 + mf][nf], 0, 0, 0);                  \
      __builtin_amdgcn_s_setprio(0);                                             \
      if (DOWAIT) asm volatile("s_waitcnt vmcnt(4)" ::: "memory");               \
      __builtin_amdgcn_s_barrier();                                              \
    }

    // ---- prologue: stage slices 0,1,2; land 0 and 1; keep 2 in flight ----
    STAGE(1, 0); STAGE(0, 0);
    STAGE(1, 1); STAGE(0, 1);
    STAGE(1, 2); STAGE(0, 2);
    asm volatile("s_waitcnt vmcnt(4)" ::: "memory");
    __builtin_amdgcn_s_barrier();

    for (int j = 0; j < NSLICE / 4; ++j) {
        const int g0 = j * 4;
        DO_PHASE(g0 + 0, 0, 1, g0 + 3, 0);
        DO_PHASE(g0 + 0, 1, 0, g0 + 3, 0);
        DO_PHASE(g0 + 1, 0, 1, g0 + 4, 0);
        DO_PHASE(g0 + 1, 1, 0, g0 + 4, 1);
        DO_PHASE(g0 + 2, 0, 1, g0 + 5, 0);
        DO_PHASE(g0 + 2, 1, 0, g0 + 5, 0);
        DO_PHASE(g0 + 3, 0, 1, g0 + 6, 0);
        DO_PHASE(g0 + 3, 1, 0, g0 + 6, 1);
    }
    asm volatile("s_waitcnt vmcnt(0)" ::: "memory");  // drain tail garbage loads

#undef DO_PHASE
#undef STAGE

    // ---- epilogue: bias + scatter into q/k/v regions ----
    float* obase; int ldo; const float* bias; int cofs;
    if (col0 < NQ) {
        obase = out;                             ldo = NQ;  bias = bq; cofs = 0;
    } else if (col0 < NQ + NKV) {
        obase = out + (size_t)Mdim * NQ;         ldo = NKV; bias = bk; cofs = NQ;
    } else {
        obase = out + (size_t)Mdim * (NQ + NKV); ldo = NKV; bias = bv; cofs = NQ + NKV;
    }

    #pragma unroll
    for (int nf = 0; nf < 4; ++nf) {
        const int col = col0 + wc * 64 + nf * 16 + (lane & 15) - cofs;
        const float b = bias[col];
        #pragma unroll
        for (int mf = 0; mf < 8; ++mf) {
            #pragma unroll
            for (int r = 0; r < 4; ++r) {
                const int row = row0 + wr * 128 + mf * 16 + (lane >> 4) * 4 + r;
                obase[(size_t)row * ldo + col] = acc[mf][nf][r] + b;
            }
        }
    }
}

// ---------------------------------------------------------------------------
extern "C" void kernel_launch(void* const* d_in, const int* in_sizes, int n_in,
                              void* d_out, int out_size, void* d_ws, size_t ws_size,
                              hipStream_t stream) {
    const float* x  = (const float*)d_in[0];
    const float* Wq = (const float*)d_in[1];
    const float* Wk = (const float*)d_in[2];
    const float* Wv = (const float*)d_in[3];
    const float* bq = (const float*)d_in[4];
    const float* bk = (const float*)d_in[5];
    const float* bv = (const float*)d_in[6];
    const float* Aq = (const float*)d_in[7];
    const float* Bq = (const float*)d_in[8];
    const float* Ak = (const float*)d_in[9];
    const float* Bk = (const float*)d_in[10];
    const float* Av = (const float*)d_in[11];
    const float* Bv = (const float*)d_in[12];
    float* out = (float*)d_out;

    unsigned short* Xbf = (unsigned short*)d_ws;                   // 64 MB
    unsigned short* Wf  = Xbf + (size_t)Mdim * Kdim;               // 48 MB

    prep_kernel<<<WEFF_BLOCKS + CVT_BLOCKS, 256, 0, stream>>>(
        (const float4*)x, Xbf, Wq, Wk, Wv, Aq, Bq, Ak, Bk, Av, Bv, Wf);

    gemm_qkv_kernel<<<NWG, 512, 0, stream>>>(Xbf, Wf, bq, bk, bv, out);
}

// Round 4
// 461.455 us; speedup vs baseline: 1.7937x; 1.5031x over previous
//
#include <hip/hip_runtime.h>

// ---------------------------------------------------------------------------
// LoRA QKV fused projection on MI355X (gfx950)
// Weff-folding (LoRA into weights) + ONE bf16 MFMA GEMM.
// GEMM: 256x256 tile, 8 waves, 8-phase schedule with counted vmcnt (T3+T4),
// both-sides LDS XOR swizzle (T2), s_setprio around MFMA (T5).
// R4: prep rewritten as tiled kernel (A transposed in LDS, coalesced W sweep)
//     — old version re-streamed A per row at 256B lane stride (278 us -> ~70).
//     GEMM: last iteration peeled (no wrap-around garbage staging).
// ---------------------------------------------------------------------------

#define GLOBAL_AS __attribute__((address_space(1)))
#define LDS_AS    __attribute__((address_space(3)))

typedef __attribute__((ext_vector_type(8))) short  short8;   // 8 bf16 (MFMA A/B frag)
typedef __attribute__((ext_vector_type(4))) float  floatx4;  // MFMA C/D frag

constexpr int Mdim = 8192;   // B*S
constexpr int Kdim = 4096;   // H
constexpr int NQ   = 4096;
constexpr int NKV  = 1024;
constexpr int NTOT = NQ + 2 * NKV;  // 6144
constexpr float LORA_SCALE = 2.0f;

constexpr int BM = 256, BN = 256;
constexpr int TILES_M = Mdim / BM;      // 32
constexpr int TILES_N = NTOT / BN;      // 24
constexpr int NWG = TILES_M * TILES_N;  // 768 (%8==0 -> bijective XCD swizzle)
constexpr int NSLICE = Kdim / 32;       // 128 K-slices of 32

// prep grid split
constexpr int WEFF_BLOCKS = (NTOT / 64) * (Kdim / 512);  // 96*8 = 768
constexpr int CVT_BLOCKS  = 2048;
constexpr int AT_STRIDE   = 516;        // padded h-stride of transposed A tile

__device__ __forceinline__ unsigned short f2bf(float f) {
    union { float f; unsigned int u; } a; a.f = f;
    unsigned int r = a.u + 0x7FFFu + ((a.u >> 16) & 1u);
    return (unsigned short)(r >> 16);
}

// ---------------------------------------------------------------------------
// Fused prep:
//   blocks [0, WEFF_BLOCKS): Weff[n,h] = W[n,h] + 2*sum_r A[h,r]B[r,n] -> bf16
//     tile = 64 n-rows x 512 h-cols. A chunk staged TRANSPOSED in LDS
//     (As_t[r][h], padded stride), B column chunk scaled in LDS. Each wave
//     hoists 16 float4 A frags to regs per 256-col pass, sweeps 16 rows with
//     coalesced float4 W loads + ushort4 Wf stores.
//   blocks [WEFF_BLOCKS, +CVT_BLOCKS): X fp32 -> bf16 (float4->ushort4).
// ---------------------------------------------------------------------------
__global__ __launch_bounds__(256)
void prep_kernel(const float4* __restrict__ x4, unsigned short* __restrict__ Xbf,
                 const float* __restrict__ Wq, const float* __restrict__ Wk,
                 const float* __restrict__ Wv,
                 const float* __restrict__ Aq, const float* __restrict__ Bq,
                 const float* __restrict__ Ak, const float* __restrict__ Bk,
                 const float* __restrict__ Av, const float* __restrict__ Bv,
                 unsigned short* __restrict__ Wf) {
    __shared__ float AsT[16 * AT_STRIDE];   // ~33 KB: A^T chunk, [r][h_local]
    __shared__ float Bsc[64 * 16];          // 4 KB: 2*B[r, n0+..] as [n][r]

    const int tid = threadIdx.x;

    if (blockIdx.x >= WEFF_BLOCKS) {
        // ---- X fp32 -> bf16 ----
        int i = (blockIdx.x - WEFF_BLOCKS) * 256 + tid;
        const int stride = CVT_BLOCKS * 256;
        const int n4 = Mdim * Kdim / 4;
        ushort4* out = (ushort4*)Xbf;
        for (; i < n4; i += stride) {
            float4 v = x4[i];
            ushort4 u;
            u.x = f2bf(v.x); u.y = f2bf(v.y); u.z = f2bf(v.z); u.w = f2bf(v.w);
            out[i] = u;
        }
        return;
    }

    // ---- Weff tile ----
    const int n0 = (blockIdx.x >> 3) * 64;      // 64-row group (never straddles seg)
    const int h0 = (blockIdx.x & 7) * 512;

    const float* W; const float* A; const float* Bm; int O; int nn0;
    if (n0 < NQ)            { W = Wq; A = Aq; Bm = Bq; O = NQ;  nn0 = n0; }
    else if (n0 < NQ + NKV) { W = Wk; A = Ak; Bm = Bk; O = NKV; nn0 = n0 - NQ; }
    else                    { W = Wv; A = Av; Bm = Bv; O = NKV; nn0 = n0 - NQ - NKV; }

    // stage A chunk transposed: float4 f = A[h0 + f/4][4*(f%4)+c], c=0..3
    {
        const float4* Af4 = (const float4*)(A) + h0 * 4;
        #pragma unroll
        for (int i = 0; i < 8; ++i) {
            const int f = i * 256 + tid;
            const float4 v = Af4[f];
            const int hl = f >> 2;
            const int r0 = (f & 3) * 4;
            AsT[(r0 + 0) * AT_STRIDE + hl] = v.x;
            AsT[(r0 + 1) * AT_STRIDE + hl] = v.y;
            AsT[(r0 + 2) * AT_STRIDE + hl] = v.z;
            AsT[(r0 + 3) * AT_STRIDE + hl] = v.w;
        }
    }
    // stage scaled B column chunk: Bsc[n][r] = 2*B[r, nn0+n]
    {
        const int nl = tid & 63;
        const int rq = tid >> 6;        // 0..3
        #pragma unroll
        for (int j = 0; j < 4; ++j) {
            const int r = rq * 4 + j;
            Bsc[nl * 16 + r] = Bm[r * O + nn0 + nl] * LORA_SCALE;
        }
    }
    __syncthreads();

    const int wv_ = tid >> 6;
    const int lane = tid & 63;

    #pragma unroll
    for (int pass = 0; pass < 2; ++pass) {
        const int hl = pass * 256 + lane * 4;   // local h of this lane's 4 cols
        float4 areg[16];
        #pragma unroll
        for (int r = 0; r < 16; ++r)
            areg[r] = *(const float4*)(&AsT[r * AT_STRIDE + hl]);

        for (int i = 0; i < 16; ++i) {
            const int nl = wv_ * 16 + i;
            const float4 w4 = *(const float4*)(W + (size_t)(nn0 + nl) * Kdim + h0 + hl);
            const float4* b4 = (const float4*)(&Bsc[nl * 16]);
            float4 d = {0.f, 0.f, 0.f, 0.f};
            #pragma unroll
            for (int q = 0; q < 4; ++q) {
                const float4 b = b4[q];
                d.x += areg[q*4+0].x * b.x + areg[q*4+1].x * b.y + areg[q*4+2].x * b.z + areg[q*4+3].x * b.w;
                d.y += areg[q*4+0].y * b.x + areg[q*4+1].y * b.y + areg[q*4+2].y * b.z + areg[q*4+3].y * b.w;
                d.z += areg[q*4+0].z * b.x + areg[q*4+1].z * b.y + areg[q*4+2].z * b.z + areg[q*4+3].z * b.w;
                d.w += areg[q*4+0].w * b.x + areg[q*4+1].w * b.y + areg[q*4+2].w * b.z + areg[q*4+3].w * b.w;
            }
            ushort4 u;
            u.x = f2bf(w4.x + d.x); u.y = f2bf(w4.y + d.y);
            u.z = f2bf(w4.z + d.z); u.w = f2bf(w4.w + d.w);
            *(ushort4*)(Wf + (size_t)(n0 + nl) * Kdim + h0 + hl) = u;
        }
    }
}

// ---------------------------------------------------------------------------
// GEMM: out[M, NTOT] = Xbf[M,K] . Wf[NTOT,K]^T + bias, scattered to q/k/v.
// LDS: A/B rings of 4 K-slices (slice = 256 rows x 32 k, 16 KB).
// Schedule ledger (8 phases per 4 slices, main loop j=0..30):
//   ph0: g0+0/Mh0, stage A(g0+3)   ph4: g0+2/Mh0, stage A(g0+5)
//   ph1: g0+0/Mh1, stage B(g0+3)   ph5: g0+2/Mh1, stage B(g0+5)
//   ph2: g0+1/Mh0, stage A(g0+4)   ph6: g0+3/Mh0, stage A(g0+6)
//   ph3: g0+1/Mh1, stage B(g0+4)   ph7: g0+3/Mh1, stage B(g0+6)
//   vmcnt(4) end of ph3/ph7. Peeled last iter (g0=124): stage only slice 127
//   at ph0/ph1; vmcnt(4) end ph3 (lands 126), vmcnt(0) end ph5 (lands 127).
// ---------------------------------------------------------------------------
__global__ __launch_bounds__(512, 2)
void gemm_qkv_kernel(const unsigned short* __restrict__ X,
                     const unsigned short* __restrict__ Wf,
                     const float* __restrict__ bq, const float* __restrict__ bk,
                     const float* __restrict__ bv,
                     float* __restrict__ out) {
    __shared__ __align__(16) unsigned short Abuf[4][8192];  // 64 KB
    __shared__ __align__(16) unsigned short Bbuf[4][8192];  // 64 KB

    const int tid  = threadIdx.x;
    const int lane = tid & 63;
    const int w    = tid >> 6;
    const int wr   = w >> 2;        // 0..1  (M half)
    const int wc   = w & 3;         // 0..3  (N quarter)

    int bid = blockIdx.x;
    bid = (bid & 7) * (NWG / 8) + (bid >> 3);   // XCD-aware, bijective (768%8==0)
    const int row0 = (bid / TILES_N) * BM;
    const int col0 = (bid % TILES_N) * BN;

    const int swz    = (((lane >> 4) ^ ((lane >> 1) & 3)) << 4);    // bytes
    const int aByte0 = (wr * 128 + (lane & 15)) * 64 + swz;
    const int bByte0 = (wc * 64  + (lane & 15)) * 64 + swz;

    const int srow = (w << 4) + (lane >> 2);                         // 0..127
    const int kswz = (((lane & 3) ^ ((lane >> 3) & 3)) << 3);        // elements
    const unsigned short* pA0 = X  + (size_t)(row0 + srow) * Kdim + kswz;
    const unsigned short* pA1 = pA0 + (size_t)128 * Kdim;
    const unsigned short* pB0 = Wf + (size_t)(col0 + srow) * Kdim + kswz;
    const unsigned short* pB1 = pB0 + (size_t)128 * Kdim;

    floatx4 acc[8][4];
    #pragma unroll
    for (int i = 0; i < 8; ++i)
        #pragma unroll
        for (int j = 0; j < 4; ++j)
            acc[i][j] = (floatx4){0.f, 0.f, 0.f, 0.f};

    short8 bf[4];

#define STAGE(MATA, SS)                                                          \
    { const int ss_ = (SS); const int st_ = (SS) & 3;                            \
      if (MATA) {                                                                \
        __builtin_amdgcn_global_load_lds((const GLOBAL_AS void*)(pA0 + ss_ * 32),\
            (LDS_AS void*)(&Abuf[st_][w * 512]),        16, 0, 0);               \
        __builtin_amdgcn_global_load_lds((const GLOBAL_AS void*)(pA1 + ss_ * 32),\
            (LDS_AS void*)(&Abuf[st_][4096 + w * 512]), 16, 0, 0);               \
      } else {                                                                   \
        __builtin_amdgcn_global_load_lds((const GLOBAL_AS void*)(pB0 + ss_ * 32),\
            (LDS_AS void*)(&Bbuf[st_][w * 512]),        16, 0, 0);               \
        __builtin_amdgcn_global_load_lds((const GLOBAL_AS void*)(pB1 + ss_ * 32),\
            (LDS_AS void*)(&Bbuf[st_][4096 + w * 512]), 16, 0, 0);               \
      } }

// WAITMODE: 0 = none, 1 = vmcnt(4), 2 = vmcnt(0)
#define DO_PHASE(G, MH, DOSTAGE, SMATA, SS, WAITMODE)                            \
    {                                                                            \
      const int slot_ = (G) & 3;                                                 \
      const char* abase_ = (const char*)Abuf + slot_ * 16384;                    \
      short8 af[4];                                                              \
      _Pragma("unroll")                                                          \
      for (int mf = 0; mf < 4; ++mf)                                             \
        af[mf] = *(const short8*)(abase_ + aByte0 + ((MH) * 4 + mf) * 1024);     \
      if ((MH) == 0) {                                                           \
        const char* bbase_ = (const char*)Bbuf + slot_ * 16384;                  \
        _Pragma("unroll")                                                        \
        for (int nf = 0; nf < 4; ++nf)                                           \
          bf[nf] = *(const short8*)(bbase_ + bByte0 + nf * 1024);                \
      }                                                                          \
      if (DOSTAGE) STAGE(SMATA, SS);                                             \
      __builtin_amdgcn_s_barrier();                                              \
      asm volatile("s_waitcnt lgkmcnt(0)");                                      \
      __builtin_amdgcn_s_setprio(1);                                             \
      _Pragma("unroll")                                                          \
      for (int mf = 0; mf < 4; ++mf)                                             \
        _Pragma("unroll")                                                        \
        for (int nf = 0; nf < 4; ++nf)                                           \
          acc[(MH) * 4 + mf][nf] = __builtin_amdgcn_mfma_f32_16x16x32_bf16(      \
              af[mf], bf[nf], acc[(MH) * 4 + mf][nf], 0, 0, 0);                  \
      __builtin_amdgcn_s_setprio(0);                                             \
      if ((WAITMODE) == 1) asm volatile("s_waitcnt vmcnt(4)" ::: "memory");      \
      if ((WAITMODE) == 2) asm volatile("s_waitcnt vmcnt(0)" ::: "memory");      \
      __builtin_amdgcn_s_barrier();                                              \
    }

    // ---- prologue: stage slices 0,1,2; land 0 and 1; keep 2 in flight ----
    STAGE(1, 0); STAGE(0, 0);
    STAGE(1, 1); STAGE(0, 1);
    STAGE(1, 2); STAGE(0, 2);
    asm volatile("s_waitcnt vmcnt(4)" ::: "memory");
    __builtin_amdgcn_s_barrier();

    for (int j = 0; j < NSLICE / 4 - 1; ++j) {
        const int g0 = j * 4;
        DO_PHASE(g0 + 0, 0, 1, 1, g0 + 3, 0);
        DO_PHASE(g0 + 0, 1, 1, 0, g0 + 3, 0);
        DO_PHASE(g0 + 1, 0, 1, 1, g0 + 4, 0);
        DO_PHASE(g0 + 1, 1, 1, 0, g0 + 4, 1);
        DO_PHASE(g0 + 2, 0, 1, 1, g0 + 5, 0);
        DO_PHASE(g0 + 2, 1, 1, 0, g0 + 5, 0);
        DO_PHASE(g0 + 3, 0, 1, 1, g0 + 6, 0);
        DO_PHASE(g0 + 3, 1, 1, 0, g0 + 6, 1);
    }
    // ---- peeled last iteration (g0 = 124): stage only slice 127 ----
    DO_PHASE(124, 0, 1, 1, 127, 0);
    DO_PHASE(124, 1, 1, 0, 127, 0);
    DO_PHASE(125, 0, 0, 0, 0,   0);
    DO_PHASE(125, 1, 0, 0, 0,   1);   // lands slice 126
    DO_PHASE(126, 0, 0, 0, 0,   0);
    DO_PHASE(126, 1, 0, 0, 0,   2);   // lands slice 127
    DO_PHASE(127, 0, 0, 0, 0,   0);
    DO_PHASE(127, 1, 0, 0, 0,   0);

#undef DO_PHASE
#undef STAGE

    // ---- epilogue: bias + scatter into q/k/v regions ----
    float* obase; int ldo; const float* bias; int cofs;
    if (col0 < NQ) {
        obase = out;                             ldo = NQ;  bias = bq; cofs = 0;
    } else if (col0 < NQ + NKV) {
        obase = out + (size_t)Mdim * NQ;         ldo = NKV; bias = bk; cofs = NQ;
    } else {
        obase = out + (size_t)Mdim * (NQ + NKV); ldo = NKV; bias = bv; cofs = NQ + NKV;
    }

    #pragma unroll
    for (int nf = 0; nf < 4; ++nf) {
        const int col = col0 + wc * 64 + nf * 16 + (lane & 15) - cofs;
        const float b = bias[col];
        #pragma unroll
        for (int mf = 0; mf < 8; ++mf) {
            #pragma unroll
            for (int r = 0; r < 4; ++r) {
                const int row = row0 + wr * 128 + mf * 16 + (lane >> 4) * 4 + r;
                obase[(size_t)row * ldo + col] = acc[mf][nf][r] + b;
            }
        }
    }
}

// ---------------------------------------------------------------------------
extern "C" void kernel_launch(void* const* d_in, const int* in_sizes, int n_in,
                              void* d_out, int out_size, void* d_ws, size_t ws_size,
                              hipStream_t stream) {
    const float* x  = (const float*)d_in[0];
    const float* Wq = (const float*)d_in[1];
    const float* Wk = (const float*)d_in[2];
    const float* Wv = (const float*)d_in[3];
    const float* bq = (const float*)d_in[4];
    const float* bk = (const float*)d_in[5];
    const float* bv = (const float*)d_in[6];
    const float* Aq = (const float*)d_in[7];
    const float* Bq = (const float*)d_in[8];
    const float* Ak = (const float*)d_in[9];
    const float* Bk = (const float*)d_in[10];
    const float* Av = (const float*)d_in[11];
    const float* Bv = (const float*)d_in[12];
    float* out = (float*)d_out;

    unsigned short* Xbf = (unsigned short*)d_ws;                   // 64 MB
    unsigned short* Wf  = Xbf + (size_t)Mdim * Kdim;               // 48 MB

    prep_kernel<<<WEFF_BLOCKS + CVT_BLOCKS, 256, 0, stream>>>(
        (const float4*)x, Xbf, Wq, Wk, Wv, Aq, Bq, Ak, Bk, Av, Bv, Wf);

    gemm_qkv_kernel<<<NWG, 512, 0, stream>>>(Xbf, Wf, bq, bk, bv, out);
}